// Round 8
// baseline (1461.000 us; speedup 1.0000x reference)
//
#include <hip/hip_runtime.h>
#include <hip/hip_bf16.h>

#define M_NODES 32768
#define BIAS_BASE 1576960   // u16 elems; f32 bias table at byte 3153920

using f16x8 = __attribute__((ext_vector_type(8))) _Float16;
using f32x4 = __attribute__((ext_vector_type(4))) float;
typedef unsigned short u16;
typedef unsigned int   u32;

__device__ __forceinline__ u16 f2h(float f){
  _Float16 h = (_Float16)f;
  return __builtin_bit_cast(u16, h);
}
__device__ __forceinline__ float h2f(u16 h){
  return (float)__builtin_bit_cast(_Float16, h);
}
__device__ __forceinline__ float tanh_fast(float x){
  float t = __builtin_amdgcn_exp2f(x * 2.8853900817779268f);
  return 1.0f - 2.0f * __builtin_amdgcn_rcpf(t + 1.0f);
}

// ---------------- prep: weights -> fp16 Wt[n][k]; biases -> f32 table ----------------
struct PrepPtrs { const float* w[16]; const float* b[16]; };

__global__ void prep_kernel(PrepPtrs pp, u16* ws){
  const int Bc[16] = {1,6,6,6,3,3,3,3,3,3,3,3,3,3,3,3};
  const int Kc[16] = {32,128,128,128,256,256,256,128,128,128,256,256,256,128,128,128};
  const int Nc[16] = {128,128,128,128,256,256,128,128,128,128,256,256,128,128,128,128};
  const int tot = 1576960;
  for (int i = blockIdx.x*blockDim.x + threadIdx.x; i < tot; i += gridDim.x*blockDim.x){
    int e = i, s = 0;
    while (true){ int sz = Bc[s]*Kc[s]*Nc[s]; if (e < sz) break; e -= sz; ++s; }
    int K = Kc[s], N = Nc[s];
    int kn = K*N;
    int b = e / kn; int r2 = e - b*kn;
    int n = r2 / K; int k = r2 - n*K;
    ws[i] = f2h(pp.w[s][(size_t)b*kn + (size_t)k*N + n]);
  }
  float* bb = (float*)(ws + BIAS_BASE);
  const int bs[16] = {128,768,768,768,768,768,384,384,384,384,768,768,384,384,384,384};
  const int btot = 8576;
  for (int i = blockIdx.x*blockDim.x + threadIdx.x; i < btot; i += gridDim.x*blockDim.x){
    int e = i, s = 0;
    while (e >= bs[s]){ e -= bs[s]; ++s; }
    bb[i] = pp.b[s][e];
  }
}

// ---------------- front 0 ----------------
__global__ __launch_bounds__(256) void front0_kernel(const float* __restrict__ feats,
                                                     const float* __restrict__ ew,
                                                     const float* __restrict__ eb,
                                                     float* __restrict__ out){
  __shared__ float fl[2048];
  const int brow = blockIdx.x * 64;
  const float* f0 = feats + (size_t)brow*32;
#pragma unroll
  for (int it = 0; it < 2; ++it){
    int idx = threadIdx.x + it*256;
    *(float4*)(&fl[idx*4]) = *(const float4*)(f0 + idx*4);
  }
  __syncthreads();
  const int col = threadIdx.x & 127, rh = threadIdx.x >> 7;
  float w[32];
#pragma unroll
  for (int k = 0; k < 32; ++k) w[k] = ew[k*128 + col];
  const float bv = eb[col];
  for (int r = 0; r < 32; ++r){
    int row = rh*32 + r;
    float acc = bv;
#pragma unroll
    for (int k = 0; k < 32; ++k) acc += fl[row*32 + k] * w[k];
    out[(size_t)(brow + row)*128 + col] = tanh_fast(acc);
  }
}

// ---------------- flags ----------------
#define F_NP8   (1u<<0)
#define F_S256  (1u<<1)
#define F_AM1   (1u<<2)
#define F_RES_SH 3
#define F_OUT_SH 5
#define F_IP    (1u<<7)
#define F_INQ   (1u<<8)
#define F_OSEL_SH 9
#define F_RESQ  (1u<<11)
#define F_BODYB (1u<<12)
#define F_ROWH  (1u<<13)
#define F_EMB   (1u<<14)
#define F_NOBAR (1u<<15)

struct StageRec { int wt; int bias; u32 fl; };

// one K-panel of MFMAs; amode passed as literal where possible so it folds
template<int MT, int NT>
__device__ __forceinline__ void panel(f32x4 (&acc)[MT][NT], f16x8 (&bc)[NT],
                                      const u16* inA, const float* inAf,
                                      int kpp, int amode, int rbase, int q, int c)
{
#pragma unroll
  for (int m = 0; m < MT; ++m){
    const int row = rbase + m*16 + c;
    if (amode == 0){
      f16x8 af = *(const f16x8*)(&inA[row*264 + kpp*32 + q*8]);
#pragma unroll
      for (int j = 0; j < NT; ++j)
        acc[m][j] = __builtin_amdgcn_mfma_f32_16x16x32_f16(af, bc[j], acc[m][j], 0, 0, 0);
    } else {
      const float* ap = inAf + row*132 + kpp*32 + q*8;
      float4 x0 = *(const float4*)(ap);
      float4 x1 = *(const float4*)(ap + 4);
      float xs[8] = {x0.x,x0.y,x0.z,x0.w,x1.x,x1.y,x1.z,x1.w};
      f16x8 ah, al;
#pragma unroll
      for (int k = 0; k < 8; ++k){
        _Float16 hi = (_Float16)xs[k];
        ah[k] = hi;
        al[k] = (_Float16)(xs[k] - (float)hi);
      }
#pragma unroll
      for (int j = 0; j < NT; ++j)
        acc[m][j] = __builtin_amdgcn_mfma_f32_16x16x32_f16(ah, bc[j], acc[m][j], 0, 0, 0);
#pragma unroll
      for (int j = 0; j < NT; ++j)
        acc[m][j] = __builtin_amdgcn_mfma_f32_16x16x32_f16(al, bc[j], acc[m][j], 0, 0, 0);
    }
  }
}

// BODY 0: MT=4,NT=2 (N=128-out ops, 64 rows). BODY 1: MT=2,NT=4 (N=256-out, row-half).
template<int BODY>
__device__ __forceinline__ void mm_body(const u16* inA, u16* outB, const u16* resB,
                                        const u16* __restrict__ wt, int wstride,
                                        const float* __restrict__ bias, float* gout,
                                        int NP, int amode, int res, int outm,
                                        int inplace, int nobar, int rbase, int phase)
{
  constexpr int MT = BODY ? 2 : 4;
  constexpr int NT = BODY ? 4 : 2;
  const int tid  = threadIdx.x;
  const int lane = tid & 63, nq = tid >> 6;
  const int q = lane >> 4, c = lane & 15;
  const float* inAf = (const float*)inA;
  float*       outF = (float*)outB;
  const float* resF = (const float*)resB;
  const int msk = NP - 1;
  const int ph = phase & msk;

  const u16* wrow[NT];
#pragma unroll
  for (int j = 0; j < NT; ++j){
    int nt_ = nq*2 + (j & 1) + (j >> 1) * 8;
    wrow[j] = wt + (size_t)(nt_*16 + c)*wstride + q*8;
  }
  f16x8 br0[NT], br1[NT];
#pragma unroll
  for (int j = 0; j < NT; ++j) br0[j] = *(const f16x8*)(wrow[j] + ph*32);
#pragma unroll
  for (int j = 0; j < NT; ++j) br1[j] = *(const f16x8*)(wrow[j] + ((ph + 1) & msk)*32);

  f32x4 acc[MT][NT];
#pragma unroll
  for (int m = 0; m < MT; ++m)
#pragma unroll
    for (int j = 0; j < NT; ++j) acc[m][j] = (f32x4){0.f,0.f,0.f,0.f};

#pragma clang loop unroll(disable)
  for (int kp = 0; kp < NP; kp += 2){
    {
      int kpp = (ph + kp) & msk;
      panel<MT,NT>(acc, br0, inA, inAf, kpp, BODY ? 0 : amode, rbase, q, c);
      if (kp + 2 < NP){
        int kn = (ph + kp + 2) & msk;
#pragma unroll
        for (int j = 0; j < NT; ++j) br0[j] = *(const f16x8*)(wrow[j] + kn*32);
      }
    }
    {
      int kpp = (ph + kp + 1) & msk;
      panel<MT,NT>(acc, br1, inA, inAf, kpp, BODY ? 0 : amode, rbase, q, c);
      if (kp + 3 < NP){
        int kn = (ph + kp + 3) & msk;
#pragma unroll
        for (int j = 0; j < NT; ++j) br1[j] = *(const f16x8*)(wrow[j] + kn*32);
      }
    }
  }
  if (inplace) __syncthreads();
#pragma unroll
  for (int j = 0; j < NT; ++j){
    int nt_ = nq*2 + (j & 1) + (j >> 1) * 8;
    int col = nt_*16 + c;
    float bv = bias[col];
#pragma unroll
    for (int m = 0; m < MT; ++m){
#pragma unroll
      for (int r = 0; r < 4; ++r){
        int row = rbase + m*16 + q*4 + r;
        float v = tanh_fast(acc[m][j][r] + bv);
        if (res == 1){ if (j < 2) v += h2f(resB[row*264 + col]); }
        else if (res == 2) v += h2f(resB[row*264 + col]);
        else if (res == 3) v += resF[row*132 + col];
        if (outm == 2)      gout[(size_t)row*128 + col] = v;
        else if (outm == 1) outF[row*132 + col] = v;
        else                outB[row*264 + col] = f2h(v);
      }
    }
  }
  if (!nobar) __syncthreads();
}

// embed: A from global fp32 feats (K=32), hi/lo split; 64 rows
__device__ __forceinline__ void embed_stage(const float* __restrict__ featsRow,
                                            u16* outB, const u16* __restrict__ wt,
                                            const float* __restrict__ bias)
{
  const int tid  = threadIdx.x;
  const int lane = tid & 63, nq = tid >> 6;
  const int q = lane >> 4, c = lane & 15;
  f16x8 bf[2];
#pragma unroll
  for (int j = 0; j < 2; ++j){
    int nt_ = nq*2 + j;
    bf[j] = *(const f16x8*)(wt + (nt_*16 + c)*32 + q*8);
  }
  f32x4 acc[4][2];
#pragma unroll
  for (int m = 0; m < 4; ++m){ acc[m][0] = (f32x4){0,0,0,0}; acc[m][1] = (f32x4){0,0,0,0}; }
#pragma unroll
  for (int m = 0; m < 4; ++m){
    int row = m*16 + c;
    const float* fp = featsRow + (size_t)row*32 + q*8;
    float4 a0 = *(const float4*)(fp);
    float4 a1 = *(const float4*)(fp + 4);
    float xs[8] = {a0.x,a0.y,a0.z,a0.w,a1.x,a1.y,a1.z,a1.w};
    f16x8 ah, al;
#pragma unroll
    for (int k = 0; k < 8; ++k){
      _Float16 hi = (_Float16)xs[k];
      ah[k] = hi;
      al[k] = (_Float16)(xs[k] - (float)hi);
    }
#pragma unroll
    for (int j = 0; j < 2; ++j){
      acc[m][j] = __builtin_amdgcn_mfma_f32_16x16x32_f16(ah, bf[j], acc[m][j], 0, 0, 0);
      acc[m][j] = __builtin_amdgcn_mfma_f32_16x16x32_f16(al, bf[j], acc[m][j], 0, 0, 0);
    }
  }
#pragma unroll
  for (int j = 0; j < 2; ++j){
    int nt_ = nq*2 + j;
    int col = nt_*16 + c;
    float bv = bias[col];
#pragma unroll
    for (int m = 0; m < 4; ++m){
#pragma unroll
      for (int r = 0; r < 4; ++r){
        int row = m*16 + q*4 + r;
        outB[row*264 + col] = f2h(tanh_fast(acc[m][j][r] + bv));
      }
    }
  }
  __syncthreads();
}

struct FrontArgs {
  const float* feats; const int* pred;
  const u16* ws;
  float* out;
  int l;
  StageRec st[23];
};

// LDS: P[64][264] + Q[64][264] u16 = 67584 B -> 2 blocks/CU (LDS-capped)
__global__ __launch_bounds__(256) void front_kernel(FrontArgs A)
{
  extern __shared__ u16 lds[];
  u16* P = lds;
  u16* Q = lds + 16896;
  const int brow = blockIdx.x * 64;
  const int ph = blockIdx.x;

  // gather: s = sum_k prev[idx[m][k]] -> P fp32 [64][132]
  {
    float* Pf = (float*)P;
    const float* prev = A.out + (size_t)(A.l - 1) * M_NODES * 128;
    const int c4 = threadIdx.x & 31;
    const int r0 = threadIdx.x >> 5;
#pragma unroll
    for (int rr = 0; rr < 8; ++rr){
      int row = r0 + rr*8;
      const int* ip = A.pred + ((size_t)(A.l - 1) * M_NODES + brow + row) * 8;
      float sx=0.f, sy=0.f, sz=0.f, sw=0.f;
#pragma unroll
      for (int p = 0; p < 8; ++p){
        const float4 v = *(const float4*)(prev + (size_t)ip[p]*128 + c4*4);
        sx += v.x; sy += v.y; sz += v.z; sw += v.w;
      }
      float4 o = {sx, sy, sz, sw};
      *(float4*)(&Pf[row*132 + c4*4]) = o;
    }
  }
  __syncthreads();

  const float* biasb = (const float*)(A.ws + BIAS_BASE);
  float* gout = A.out + ((size_t)A.l * M_NODES + brow) * 128;

#pragma clang loop unroll(disable)
  for (int s = 0; s < 23; ++s){
    const int wt_off = A.st[s].wt;
    const int b_off  = A.st[s].bias;
    const u32 fl     = A.st[s].fl;
    if (fl & F_EMB){
      embed_stage(A.feats + ((size_t)A.l * M_NODES + brow) * 32, Q, A.ws, biasb);
      continue;
    }
    const u16* wt   = A.ws + wt_off;
    const int wstride = (fl & F_S256) ? 256 : 128;
    const int NP      = (fl & F_NP8) ? 8 : 4;
    const int amode   = (fl & F_AM1) ? 1 : 0;
    const int res     = (fl >> F_RES_SH) & 3;
    const int outm    = (fl >> F_OUT_SH) & 3;
    const int ip      = (fl & F_IP) ? 1 : 0;
    const u16* inA    = (fl & F_INQ) ? Q : P;
    const int osel    = (fl >> F_OSEL_SH) & 3;
    u16* outB = (osel == 0) ? P : ((osel == 1) ? Q : (Q + 128));
    const u16* resB   = (fl & F_RESQ) ? Q : P;
    const int nobar   = (fl & F_NOBAR) ? 1 : 0;
    const float* bias = biasb + b_off;
    if (fl & F_BODYB)
      mm_body<1>(inA, outB, resB, wt, wstride, bias, gout, NP, 0, res, outm, ip, nobar,
                 (fl & F_ROWH) ? 32 : 0, ph);
    else
      mm_body<0>(inA, outB, resB, wt, wstride, bias, gout, NP, amode, res, outm, ip, nobar, 0, ph);
  }
}

static inline u32 mkfl(int np8,int s256,int am1,int res,int outm,int ip,int inq,int osel,int resq,
                       int bodyb,int rowh,int emb,int nobar){
  return (u32)(np8) | (u32)(s256<<1) | (u32)(am1<<2) | (u32)(res<<F_RES_SH) | (u32)(outm<<F_OUT_SH)
       | (u32)(ip<<7) | (u32)(inq<<8) | (u32)(osel<<F_OSEL_SH) | (u32)(resq<<11)
       | (u32)(bodyb<<12) | (u32)(rowh<<13) | (u32)(emb<<14) | (u32)(nobar<<15);
}

extern "C" void kernel_launch(void* const* d_in, const int* in_sizes, int n_in,
                              void* d_out, int out_size, void* d_ws, size_t ws_size,
                              hipStream_t stream)
{
  (void)in_sizes; (void)n_in; (void)out_size; (void)ws_size;
  const float* feats = (const float*)d_in[0];
  const int*   pred  = (const int*)d_in[1];
  u16*   ws  = (u16*)d_ws;
  float* out = (float*)d_out;

  PrepPtrs pp;
  const int wIdx[16] = {2,4,6,8,10,12,14,16,18,20,22,24,26,28,30,32};
  const int bIdx[16] = {3,5,7,9,11,13,15,17,19,21,23,25,27,29,31,33};
  for (int i = 0; i < 16; ++i){ pp.w[i] = (const float*)d_in[wIdx[i]]; pp.b[i] = (const float*)d_in[bIdx[i]]; }
  prep_kernel<<<2048, 256, 0, stream>>>(pp, ws);

  front0_kernel<<<M_NODES/64, 256, 0, stream>>>(feats, (const float*)d_in[2], (const float*)d_in[3], out);

  const size_t LDSB = (size_t)(2*64*264) * sizeof(u16); // 67584 B
  (void)hipFuncSetAttribute((const void*)front_kernel,
                            hipFuncAttributeMaxDynamicSharedMemorySize, (int)LDSB);

  FrontArgs A;
  A.feats = feats; A.pred = pred; A.ws = ws; A.out = out;

  for (int l = 1; l < 8; ++l){
    A.l = l;
    const int d = (l - 1 < 2) ? (l - 1) : 2;
    const int d0 = d*2, d1 = d*2 + 1;
    StageRec* S = A.st;
    //                  wt                 bias          np8 s256 am1 res out ip inq osel resq B rowh emb nobar
    S[0]  = {4096    + d0*16384, 128  + d0*128, mkfl(0,0,1, 0,0,0, 0,1,0, 0,0,0,0)}; // h1=f(s.f32)      P->Q
    S[1]  = {102400  + d0*16384, 896  + d0*128, mkfl(0,0,0, 3,1,0, 1,0,0, 0,0,0,0)}; // h2s=f(h1)+s      Q->P.f32
    S[2]  = {200704  + d0*16384, 1664 + d0*128, mkfl(0,0,1, 0,0,0, 0,1,0, 0,0,0,0)}; // r1=f(h2s.f32)    P->Q
    S[3]  = {4096    + d1*16384, 128  + d1*128, mkfl(0,0,0, 0,0,0, 1,0,0, 0,0,0,0)}; // h1b=f(r1)        Q->P
    S[4]  = {102400  + d1*16384, 896  + d1*128, mkfl(0,0,0, 2,1,1, 0,0,1, 0,0,0,0)}; // h2r=f(h1b)+r1    P->P.f32 IP
    S[5]  = {200704  + d1*16384, 1664 + d1*128, mkfl(0,0,1, 0,0,0, 0,2,0, 0,0,0,0)}; // r=f(h2r.f32)     P->Q+128
    S[6]  = {0, 0,                               mkfl(0,0,0, 0,0,0, 0,0,0, 0,0,1,0)}; // e=embed          ->Q[0:128)
    S[7]  = {299008  + d*65536,  2432 + d*256,  mkfl(0,1,0, 0,0,0, 1,0,0, 1,0,0,1)}; // cw1 h0 (K=128)   Q->P wide
    S[8]  = {299008  + d*65536,  2432 + d*256,  mkfl(0,1,0, 0,0,0, 1,0,0, 1,1,0,0)}; // cw1 h1
    S[9]  = {495616  + d*65536,  3200 + d*256,  mkfl(1,1,0, 1,0,1, 0,0,1, 1,0,0,1)}; // cw2 h0 +[e,0] IP P->P
    S[10] = {495616  + d*65536,  3200 + d*256,  mkfl(1,1,0, 1,0,1, 0,0,1, 1,1,0,0)}; // cw2 h1
    S[11] = {692224  + d*32768,  3968 + d*128,  mkfl(1,1,0, 0,0,0, 0,1,0, 0,0,0,0)}; // cw3 (K=256)      P->Q
    S[12] = {790528  + d*16384,  4352 + d*128,  mkfl(0,0,0, 0,0,0, 1,0,0, 0,0,0,0)}; // ch1              Q->P
    S[13] = {839680  + d*16384,  4736 + d*128,  mkfl(0,0,0, 2,0,1, 0,0,1, 0,0,0,0)}; // ch2 +e2 IP       P->P
    S[14] = {888832  + d*16384,  5120 + d*128,  mkfl(0,0,0, 0,0,0, 0,1,0, 0,0,0,0)}; // ch3 -> e''       P->Q
    S[15] = {937984  + d*65536,  5504 + d*256,  mkfl(1,1,0, 0,0,0, 1,0,0, 1,0,0,1)}; // nw1 h0 (K=256)   Q->P
    S[16] = {937984  + d*65536,  5504 + d*256,  mkfl(1,1,0, 0,0,0, 1,0,0, 1,1,0,0)}; // nw1 h1
    S[17] = {1134592 + d*65536,  6272 + d*256,  mkfl(1,1,0, 2,0,1, 0,0,1, 1,0,0,1)}; // nw2 h0 +x2 IP    P->P
    S[18] = {1134592 + d*65536,  6272 + d*256,  mkfl(1,1,0, 2,0,1, 0,0,1, 1,1,0,0)}; // nw2 h1
    S[19] = {1331200 + d*32768,  7040 + d*128,  mkfl(1,1,0, 0,0,0, 0,1,0, 0,0,0,0)}; // nw3 -> e3        P->Q
    S[20] = {1429504 + d*16384,  7424 + d*128,  mkfl(0,0,0, 0,0,0, 1,0,0, 0,0,0,0)}; // nh1              Q->P
    S[21] = {1478656 + d*16384,  7808 + d*128,  mkfl(0,0,0, 2,0,1, 0,0,1, 0,0,0,0)}; // nh2 +e3 IP       P->P
    S[22] = {1527808 + d*16384,  8192 + d*128,  mkfl(0,0,0, 0,2,0, 0,0,0, 0,0,0,1)}; // nh3 -> global
    front_kernel<<<M_NODES/64, 256, LDSB, stream>>>(A);
  }
}

// Round 9
// 662.652 us; speedup vs baseline: 2.2048x; 2.2048x over previous
//
#include <hip/hip_runtime.h>
#include <hip/hip_bf16.h>

#define M_NODES 32768

using f16x8 = __attribute__((ext_vector_type(8))) _Float16;
using f16x4 = __attribute__((ext_vector_type(4))) _Float16;
using f32x4 = __attribute__((ext_vector_type(4))) float;
typedef unsigned short u16;
typedef unsigned int   u32;

__device__ __forceinline__ u16 f2h(float f){
  _Float16 h = (_Float16)f;
  return __builtin_bit_cast(u16, h);
}
__device__ __forceinline__ float h2f(u16 h){
  return (float)__builtin_bit_cast(_Float16, h);
}
// tanh(x) = 1 - 2/(e^{2x}+1); saturates correctly at +-inf
__device__ __forceinline__ float tanh_fast(float x){
  float t = __builtin_amdgcn_exp2f(x * 2.8853900817779268f);
  return 1.0f - 2.0f * __builtin_amdgcn_rcpf(t + 1.0f);
}

// ---------------- prep: fp32 weights -> fp16 transposed Wt[n][k] in d_ws ----------------
struct PrepPtrs { const float* p[16]; };

__global__ void prep_kernel(PrepPtrs pp, u16* ws){
  const int Bc[16] = {1,6,6,6,3,3,3,3,3,3,3,3,3,3,3,3};
  const int Kc[16] = {32,128,128,128,256,256,256,128,128,128,256,256,256,128,128,128};
  const int Nc[16] = {128,128,128,128,256,256,128,128,128,128,256,256,128,128,128,128};
  const int tot = 1576960;
  for (int i = blockIdx.x*blockDim.x + threadIdx.x; i < tot; i += gridDim.x*blockDim.x){
    int e = i, s = 0;
    while (true){ int sz = Bc[s]*Kc[s]*Nc[s]; if (e < sz) break; e -= sz; ++s; }
    int K = Kc[s], N = Nc[s];
    int kn = K*N;
    int b = e / kn; int r2 = e - b*kn;
    int n = r2 / K; int k = r2 - n*K;
    float v = pp.p[s][(size_t)b*kn + (size_t)k*N + n];
    ws[i] = f2h(v);
  }
}

// ---------------- front 0: e0 = tanh(feats0 @ embed_w + b) (fp32 vector ALU, exact) ----------------
__global__ __launch_bounds__(256) void front0_kernel(const float* __restrict__ feats,
                                                     const float* __restrict__ ew,
                                                     const float* __restrict__ eb,
                                                     float* __restrict__ out){
  __shared__ float fl[2048]; // 64 rows x 32 feats
  const int brow = blockIdx.x * 64;
  const float* f0 = feats + (size_t)brow*32;
#pragma unroll
  for (int it = 0; it < 2; ++it){
    int idx = threadIdx.x + it*256;
    *(float4*)(&fl[idx*4]) = *(const float4*)(f0 + idx*4);
  }
  __syncthreads();
  const int col = threadIdx.x & 127, rh = threadIdx.x >> 7;
  float w[32];
#pragma unroll
  for (int k = 0; k < 32; ++k) w[k] = ew[k*128 + col];
  const float bv = eb[col];
  for (int r = 0; r < 32; ++r){
    int row = rh*32 + r;
    float acc = bv;
#pragma unroll
    for (int k = 0; k < 32; ++k) acc += fl[row*32 + k] * w[k];
    out[(size_t)(brow + row)*128 + col] = tanh_fast(acc);
  }
}

// ---------------- generic MFMA stage (fp16 MFMA, fp32 accumulate) ----------------
// 64-row block, 4 waves (wave nq owns col tiles). SWAPPED OPERANDS: mfma(W, act)
// so the D-fragment holds 4 CONSECUTIVE OUTPUT COLUMNS of one row per thread:
//   D col index (lane&15=c) = act row; D row index (q*4+r) = W col n.
// -> epilogue does vectorized b64/float4 LDS+global stores instead of 32 scalars.
// B-fragments (weights) direct from global (L2-resident d_ws), depth-2 ring,
// per-block K-panel phase rotation (numerically benign, accumulation commutes).
// LDS act buffers: u16 row stride 264 (f16 view) == float row stride 132 (f32 view).
// act-frag: row = m*16 + (lane&15), k = (lane>>4)*8+j ; W-frag from Wt[n][k] rows.
// AMODE: 0 = act fp16 in LDS, 1 = act fp32 in LDS -> hi/lo split (2x MFMA)
// RESMODE: 0 none, 1 fp16 res col<128 only, 2 fp16 res, 3 fp32 res
// OUTMODE: 0 fp16 LDS, 1 fp32 LDS, 2 fp32 global (final)
template<int KLOOP, int N, int WS, int AMODE, int RESMODE, int OUTMODE, bool INPLACE>
__device__ __forceinline__ void mm_stage(const u16* inA, u16* outB, const u16* resB,
                                         const u16* __restrict__ wt,
                                         const float* __restrict__ bias,
                                         float* gout, int phase)
{
  const int tid  = threadIdx.x;
  const int lane = tid & 63, nq = tid >> 6;
  const int q = lane >> 4, c = lane & 15;
  constexpr int NT = N / 64;      // col tiles per wave (2 or 4)
  constexpr int NP = KLOOP / 32;  // k-panels (4 or 8)
  const float* inAf = (const float*)inA;
  float*       outF = (float*)outB;
  const float* resF = (const float*)resB;
  const int msk = NP - 1;
  const int ph = phase & msk;

  const u16* wrow[NT];
#pragma unroll
  for (int j = 0; j < NT; ++j){
    int nt = nq*2 + (j & 1) + (j >> 1) * 8;
    wrow[j] = wt + (size_t)(nt*16 + c)*WS + q*8;
  }
  // depth-2 register ring, rotated start
  f16x8 breg[2][NT];
#pragma unroll
  for (int j = 0; j < NT; ++j) breg[0][j] = *(const f16x8*)(wrow[j] + ph*32);
#pragma unroll
  for (int j = 0; j < NT; ++j) breg[1][j] = *(const f16x8*)(wrow[j] + ((ph + 1) & msk)*32);

  f32x4 acc[4][NT];
#pragma unroll
  for (int m = 0; m < 4; ++m)
#pragma unroll
    for (int j = 0; j < NT; ++j) acc[m][j] = (f32x4){0.f,0.f,0.f,0.f};

#pragma unroll
  for (int kp = 0; kp < NP; ++kp){
    const int slot = kp & 1;
    const int kpp = (ph + kp) & msk;
    f16x8 bc[NT];
#pragma unroll
    for (int j = 0; j < NT; ++j) bc[j] = breg[slot][j];
    if (kp + 2 < NP){
      int kn = (ph + kp + 2) & msk;
#pragma unroll
      for (int j = 0; j < NT; ++j) breg[slot][j] = *(const f16x8*)(wrow[j] + kn*32);
    }
#pragma unroll
    for (int m = 0; m < 4; ++m){
      if (AMODE == 0){
        f16x8 af = *(const f16x8*)(&inA[(m*16 + c)*264 + kpp*32 + q*8]);
#pragma unroll
        for (int j = 0; j < NT; ++j)
          acc[m][j] = __builtin_amdgcn_mfma_f32_16x16x32_f16(bc[j], af, acc[m][j], 0, 0, 0);
      } else {
        const float* ap = inAf + (m*16 + c)*132 + kpp*32 + q*8;
        float4 x0 = *(const float4*)(ap);
        float4 x1 = *(const float4*)(ap + 4);
        float xs[8] = {x0.x,x0.y,x0.z,x0.w,x1.x,x1.y,x1.z,x1.w};
        f16x8 ah, al;
#pragma unroll
        for (int k = 0; k < 8; ++k){
          _Float16 hi = (_Float16)xs[k];
          ah[k] = hi;
          al[k] = (_Float16)(xs[k] - (float)hi);
        }
#pragma unroll
        for (int j = 0; j < NT; ++j){
          acc[m][j] = __builtin_amdgcn_mfma_f32_16x16x32_f16(bc[j], ah, acc[m][j], 0, 0, 0);
          acc[m][j] = __builtin_amdgcn_mfma_f32_16x16x32_f16(bc[j], al, acc[m][j], 0, 0, 0);
        }
      }
    }
  }
  if (INPLACE) __syncthreads();
  // vectorized epilogue: per (j,m) one row (m*16+c), 4 consecutive cols (nt*16+q*4 ..+3)
#pragma unroll
  for (int j = 0; j < NT; ++j){
    int nt = nq*2 + (j & 1) + (j >> 1) * 8;
    int col0 = nt*16 + q*4;
    float4 bq = *(const float4*)(bias + col0);
    float bvv[4] = {bq.x, bq.y, bq.z, bq.w};
#pragma unroll
    for (int m = 0; m < 4; ++m){
      int row = m*16 + c;
      float v[4];
#pragma unroll
      for (int r = 0; r < 4; ++r) v[r] = tanh_fast(acc[m][j][r] + bvv[r]);
      if (RESMODE == 2 || (RESMODE == 1 && j < 2)){
        f16x4 rv = *(const f16x4*)(&resB[row*264 + col0]);
#pragma unroll
        for (int r = 0; r < 4; ++r) v[r] += (float)rv[r];
      } else if (RESMODE == 3){
        float4 rf = *(const float4*)(&resF[row*132 + col0]);
        v[0] += rf.x; v[1] += rf.y; v[2] += rf.z; v[3] += rf.w;
      }
      if (OUTMODE == 2){
        float4 o = {v[0], v[1], v[2], v[3]};
        *(float4*)(&gout[(size_t)row*128 + col0]) = o;
      } else if (OUTMODE == 1){
        float4 o = {v[0], v[1], v[2], v[3]};
        *(float4*)(&outF[row*132 + col0]) = o;
      } else {
        f16x4 h;
#pragma unroll
        for (int r = 0; r < 4; ++r) h[r] = (_Float16)v[r];
        *(f16x4*)(&outB[row*264 + col0]) = h;
      }
    }
  }
  __syncthreads();
}

// embed stage: act from global fp32 feats (K=32) hi/lo split; swapped operands too
__device__ __forceinline__ void embed_stage(const float* __restrict__ featsRow,
                                            u16* outB, const u16* __restrict__ wt,
                                            const float* __restrict__ bias)
{
  const int tid  = threadIdx.x;
  const int lane = tid & 63, nq = tid >> 6;
  const int q = lane >> 4, c = lane & 15;
  f16x8 bf[2];
#pragma unroll
  for (int j = 0; j < 2; ++j){
    int nt = nq*2 + j;
    bf[j] = *(const f16x8*)(wt + (nt*16 + c)*32 + q*8);
  }
  f32x4 acc[4][2];
#pragma unroll
  for (int m = 0; m < 4; ++m){ acc[m][0] = (f32x4){0,0,0,0}; acc[m][1] = (f32x4){0,0,0,0}; }
#pragma unroll
  for (int m = 0; m < 4; ++m){
    int row = m*16 + c;
    const float* fp = featsRow + (size_t)row*32 + q*8;
    float4 a0 = *(const float4*)(fp);
    float4 a1 = *(const float4*)(fp + 4);
    float xs[8] = {a0.x,a0.y,a0.z,a0.w,a1.x,a1.y,a1.z,a1.w};
    f16x8 ah, al;
#pragma unroll
    for (int k = 0; k < 8; ++k){
      _Float16 hi = (_Float16)xs[k];
      ah[k] = hi;
      al[k] = (_Float16)(xs[k] - (float)hi);
    }
#pragma unroll
    for (int j = 0; j < 2; ++j){
      acc[m][j] = __builtin_amdgcn_mfma_f32_16x16x32_f16(bf[j], ah, acc[m][j], 0, 0, 0);
      acc[m][j] = __builtin_amdgcn_mfma_f32_16x16x32_f16(bf[j], al, acc[m][j], 0, 0, 0);
    }
  }
#pragma unroll
  for (int j = 0; j < 2; ++j){
    int nt = nq*2 + j;
    int col0 = nt*16 + q*4;
    float4 bq = *(const float4*)(bias + col0);
    float bvv[4] = {bq.x, bq.y, bq.z, bq.w};
#pragma unroll
    for (int m = 0; m < 4; ++m){
      int row = m*16 + c;
      f16x4 h;
#pragma unroll
      for (int r = 0; r < 4; ++r) h[r] = (_Float16)tanh_fast(acc[m][j][r] + bvv[r]);
      *(f16x4*)(&outB[row*264 + col0]) = h;
    }
  }
  __syncthreads();
}

struct FrontArgs {
  const float* feats; const int* pred;
  const u16* ws;
  float* out;
  const float* embed_b;
  const float* mp_b1; const float* mp_b2; const float* mp_b3;
  const float* cw_b1; const float* cw_b2; const float* cw_b3;
  const float* ch_b1; const float* ch_b2; const float* ch_b3;
  const float* nw_b1; const float* nw_b2; const float* nw_b3;
  const float* nh_b1; const float* nh_b2; const float* nh_b3;
  int l, d;
};

// LDS: P[64][264] u16 + Q[64][264] u16 = 67584 B dynamic -> 2 blocks/CU
__global__ __launch_bounds__(256, 2) void front_kernel(FrontArgs A)
{
  extern __shared__ u16 lds[];
  u16* P  = lds;
  u16* Q  = lds + 16896;
  const int brow = blockIdx.x * 64;
  const int d = A.d;
  const u16* ws = A.ws;
  const int ph = blockIdx.x;   // per-block K-panel phase

  // ---- gather: s = sum_k prev[idx[m][k]] -> P as fp32 [64][132] ----
  {
    float* Pf = (float*)P;
    const float* prev = A.out + (size_t)(A.l - 1) * M_NODES * 128;
    const int c4 = threadIdx.x & 31;  // float4 column group
    const int r0 = threadIdx.x >> 5;  // 8 rows in flight
#pragma unroll
    for (int rr = 0; rr < 8; ++rr){
      int row = r0 + rr*8;
      const int* ip = A.pred + ((size_t)(A.l - 1) * M_NODES + brow + row) * 8;
      float sx=0.f, sy=0.f, sz=0.f, sw=0.f;
#pragma unroll
      for (int p = 0; p < 8; ++p){
        const float4 v = *(const float4*)(prev + (size_t)ip[p]*128 + c4*4);
        sx += v.x; sy += v.y; sz += v.z; sw += v.w;
      }
      float4 o = {sx, sy, sz, sw};
      *(float4*)(&Pf[row*132 + c4*4]) = o;
    }
  }
  __syncthreads();

  const int d0 = d*2, d1 = d*2 + 1;
  // 1. h1 = tanh(s @ w1)               A=P.f32 -> Q.f16[0:128)
  mm_stage<128,128,128, 1,0,0,false>(P, Q, nullptr, ws + 4096   + (size_t)d0*16384, A.mp_b1 + d0*128, nullptr, ph);
  // 2. h2s = tanh(h1 @ w2) + s         A=Q.f16, res=P.f32 -> P.f32 (per-thread identity, safe)
  mm_stage<128,128,128, 0,3,1,false>(Q, P, P,       ws + 102400 + (size_t)d0*16384, A.mp_b2 + d0*128, nullptr, ph);
  // 3. r1 = tanh(h2s @ w3)             A=P.f32 -> Q.f16[0:128)
  mm_stage<128,128,128, 1,0,0,false>(P, Q, nullptr, ws + 200704 + (size_t)d0*16384, A.mp_b3 + d0*128, nullptr, ph);
  // 4. h1b = tanh(r1 @ w1)             A=Q.f16 -> P.f16[0:128)
  mm_stage<128,128,128, 0,0,0,false>(Q, P, nullptr, ws + 4096   + (size_t)d1*16384, A.mp_b1 + d1*128, nullptr, ph);
  // 5. h2r = tanh(h1b @ w2) + r1       A=P.f16, res=Q.f16 -> P.f32 (layout change: INPLACE)
  mm_stage<128,128,128, 0,2,1,true >(P, P, Q,       ws + 102400 + (size_t)d1*16384, A.mp_b2 + d1*128, nullptr, ph);
  // 6. r = tanh(h2r @ w3)              A=P.f32 -> Q.f16[128:256)
  mm_stage<128,128,128, 1,0,0,false>(P, Q + 128, nullptr, ws + 200704 + (size_t)d1*16384, A.mp_b3 + d1*128, nullptr, ph);
  // 7. e -> Q.f16[0:128)   (Q = [e | r])
  embed_stage(A.feats + ((size_t)A.l * M_NODES + brow) * 32, Q, ws, A.embed_b);
  // ---- comb_wide resnet on [e,0] (zero-trick: K=128) ----
  mm_stage<128,256,256, 0,0,0,false>(Q, P, nullptr, ws + 299008 + (size_t)d*65536, A.cw_b1 + d*256, nullptr, ph);
  mm_stage<256,256,256, 0,1,0,true >(P, P, Q,       ws + 495616 + (size_t)d*65536, A.cw_b2 + d*256, nullptr, ph);
  mm_stage<256,128,256, 0,0,0,false>(P, Q, nullptr, ws + 692224 + (size_t)d*32768, A.cw_b3 + d*128, nullptr, ph);
  // ---- comb_h resnet ----
  mm_stage<128,128,128, 0,0,0,false>(Q, P, nullptr, ws + 790528 + (size_t)d*16384, A.ch_b1 + d*128, nullptr, ph);
  mm_stage<128,128,128, 0,2,0,true >(P, P, Q,       ws + 839680 + (size_t)d*16384, A.ch_b2 + d*128, nullptr, ph);
  mm_stage<128,128,128, 0,0,0,false>(P, Q, nullptr, ws + 888832 + (size_t)d*16384, A.ch_b3 + d*128, nullptr, ph);
  // ---- node_wide resnet on x2 = [e''|r] in Q ----
  mm_stage<256,256,256, 0,0,0,false>(Q, P, nullptr, ws + 937984  + (size_t)d*65536, A.nw_b1 + d*256, nullptr, ph);
  mm_stage<256,256,256, 0,2,0,true >(P, P, Q,       ws + 1134592 + (size_t)d*65536, A.nw_b2 + d*256, nullptr, ph);
  mm_stage<256,128,256, 0,0,0,false>(P, Q, nullptr, ws + 1331200 + (size_t)d*32768, A.nw_b3 + d*128, nullptr, ph);
  // ---- node_h resnet; final writes fp32 to global (vectorized float4) ----
  mm_stage<128,128,128, 0,0,0,false>(Q, P, nullptr, ws + 1429504 + (size_t)d*16384, A.nh_b1 + d*128, nullptr, ph);
  mm_stage<128,128,128, 0,2,0,true >(P, P, Q,       ws + 1478656 + (size_t)d*16384, A.nh_b2 + d*128, nullptr, ph);
  float* gout = A.out + ((size_t)A.l * M_NODES + brow) * 128;
  mm_stage<128,128,128, 0,0,2,false>(P, nullptr, nullptr, ws + 1527808 + (size_t)d*16384, A.nh_b3 + d*128, gout, ph);
}

extern "C" void kernel_launch(void* const* d_in, const int* in_sizes, int n_in,
                              void* d_out, int out_size, void* d_ws, size_t ws_size,
                              hipStream_t stream)
{
  (void)in_sizes; (void)n_in; (void)out_size; (void)ws_size;
  const float* feats = (const float*)d_in[0];
  const int*   pred  = (const int*)d_in[1];
  u16*   ws  = (u16*)d_ws;
  float* out = (float*)d_out;

  PrepPtrs pp;
  const int wIdx[16] = {2,4,6,8,10,12,14,16,18,20,22,24,26,28,30,32};
  for (int i = 0; i < 16; ++i) pp.p[i] = (const float*)d_in[wIdx[i]];
  prep_kernel<<<2048, 256, 0, stream>>>(pp, ws);

  front0_kernel<<<M_NODES/64, 256, 0, stream>>>(feats, (const float*)d_in[2], (const float*)d_in[3], out);

  const size_t LDSB = (size_t)(2*64*264) * sizeof(u16); // 67584 B
  (void)hipFuncSetAttribute((const void*)front_kernel,
                            hipFuncAttributeMaxDynamicSharedMemorySize, (int)LDSB);

  FrontArgs A;
  A.feats = feats; A.pred = pred; A.ws = ws; A.out = out;
  A.embed_b = (const float*)d_in[3];
  A.mp_b1 = (const float*)d_in[5];  A.mp_b2 = (const float*)d_in[7];  A.mp_b3 = (const float*)d_in[9];
  A.cw_b1 = (const float*)d_in[11]; A.cw_b2 = (const float*)d_in[13]; A.cw_b3 = (const float*)d_in[15];
  A.ch_b1 = (const float*)d_in[17]; A.ch_b2 = (const float*)d_in[19]; A.ch_b3 = (const float*)d_in[21];
  A.nw_b1 = (const float*)d_in[23]; A.nw_b2 = (const float*)d_in[25]; A.nw_b3 = (const float*)d_in[27];
  A.nh_b1 = (const float*)d_in[29]; A.nh_b2 = (const float*)d_in[31]; A.nh_b3 = (const float*)d_in[33];

  for (int l = 1; l < 8; ++l){
    A.l = l;
    A.d = (l - 1 < 2) ? (l - 1) : 2;
    front_kernel<<<M_NODES/64, 256, LDSB, stream>>>(A);
  }
}